// Round 11
// baseline (106.200 us; speedup 1.0000x reference)
//
#include <hip/hip_runtime.h>
#include <hip/hip_bf16.h>
#include <math.h>

#define NH 16
#define QL 2048
#define SL 2048
#define DD 64
#define BQ 128
#define NSPLIT 4
#define PSTR 72
#define QK_SCALE_LOG2E 0.1803368801111f   // (8/64) * log2(e): fold softmax scale + ln2 into Q

typedef __attribute__((ext_vector_type(8))) short short8;
typedef __attribute__((ext_vector_type(4))) float floatx4;
typedef __attribute__((ext_vector_type(4))) unsigned short ushort4v;
typedef __attribute__((ext_vector_type(8))) unsigned short ushort8v;

__device__ __forceinline__ unsigned short f2bf(float x) {   // RNE fp32->bf16
    unsigned u = __float_as_uint(x);
    u += 0x7FFFu + ((u >> 16) & 1u);
    return (unsigned short)(u >> 16);
}
__device__ __forceinline__ unsigned int f2bf2u(float x, float y) {  // packed pair (low=x)
    __hip_bfloat162 h = __float22bfloat162_rn(make_float2(x, y));
    return *(unsigned int*)&h;
}
__device__ __forceinline__ float bf2f(unsigned short h) {
    return __uint_as_float((unsigned)h << 16);
}

// async global->LDS, 16B per lane; LDS dest = wave-uniform base + lane*16
__device__ __forceinline__ void gld16(const unsigned short* g, unsigned short* l) {
    __builtin_amdgcn_global_load_lds(
        (const __attribute__((address_space(1))) unsigned int*)g,
        (__attribute__((address_space(3))) unsigned int*)l, 16, 0, 0);
}

// ---------------- prep: Q->bf16(prescaled) + K->bf16 + V->V^T bf16 ----------------
__global__ __launch_bounds__(512) void k_prep(
    const float* __restrict__ Qf, const float* __restrict__ Kf, const float* __restrict__ Vf,
    unsigned short* __restrict__ Qb, unsigned short* __restrict__ Kb, unsigned short* __restrict__ Vtb)
{
    __shared__ unsigned short sT[64][PSTR];    // 9 KB: V-transpose scratch
    const int bx = (int)blockIdx.x, tid = (int)threadIdx.x;
    const int gidx = bx * 512 + tid;

    // K convert: NH*SL*DD/4 = 524288 float4 groups, 2 per thread
    #pragma unroll
    for (int k = 0; k < 2; ++k) {
        int idx = gidx + k * (512 * 512);
        float4 v = ((const float4*)Kf)[idx];
        ushort4v h = { f2bf(v.x), f2bf(v.y), f2bf(v.z), f2bf(v.w) };
        *(ushort4v*)(Kb + (size_t)idx * 4) = h;
    }
    // Q convert with softmax scale folded (matches prior in-attn conversion numerics)
    #pragma unroll
    for (int k = 0; k < 2; ++k) {
        int idx = gidx + k * (512 * 512);
        float4 v = ((const float4*)Qf)[idx];
        const float S = QK_SCALE_LOG2E;
        ushort4v h = { f2bf(v.x * S), f2bf(v.y * S), f2bf(v.z * S), f2bf(v.w * S) };
        *(ushort4v*)(Qb + (size_t)idx * 4) = h;
    }

    // V transpose: block bx owns s-tile bx (16 heads x 32 tiles = 512)
    const int n = bx >> 5, s0 = (bx & 31) * 64;
    const float* vb = Vf + ((size_t)n * SL + s0) * DD;
    #pragma unroll
    for (int i = 0; i < 2; ++i) {
        int idx = tid + i * 512;
        int r = idx >> 4, c = (idx & 15) << 2;
        float4 v = *(const float4*)(vb + r * DD + c);
        sT[c + 0][r] = f2bf(v.x);
        sT[c + 1][r] = f2bf(v.y);
        sT[c + 2][r] = f2bf(v.z);
        sT[c + 3][r] = f2bf(v.w);
    }
    __syncthreads();
    const int d = tid >> 3, sg = tid & 7;
    unsigned short* out = Vtb + (size_t)n * DD * SL + (size_t)d * SL + s0 + sg * 8;
    ushort8v a;
    #pragma unroll
    for (int i = 0; i < 8; ++i) a[i] = sT[d][sg * 8 + i];
    *(ushort8v*)out = a;
}

// ---------------- attention: R9 pair-pipeline, parity-4 split-S ----------------
// Split sp owns s-tiles with (tile & 3) == sp. Diag tiles d0=2*qt (parity in {0,2}) and d0+1
// (parity in {1,3}) -> exactly 2 of 4 splits have a diag tile; blocks may have total==0
// (uniform early-exit; combine predicate matches). Longest chain: <=9 tiles (vs 17 at NSPLIT=2)
// -> attacks the measured makespan = max-chain x 1.3us/tile law (R7/R9/R10 counters).
__global__ __launch_bounds__(512, 4) void k_attn(
    const unsigned short* __restrict__ Qb, const unsigned short* __restrict__ Kb,
    const unsigned short* __restrict__ Vtb, const int* __restrict__ plen_g,
    unsigned short* __restrict__ Opb, float* __restrict__ Lp)
{
    // K/V: 64x64 bf16 tiles, row = 64 ushorts (128B, NO pad: global_load_lds needs lane*16 dest),
    // chunk c of row r at slot c ^ (r&7) (swizzle on the global fetch side).
    __shared__ unsigned short sK[4][64 * 64];    // 32 KB: 2 pairs x 2 tiles
    __shared__ unsigned short sVt[4][64 * 64];   // 32 KB
    __shared__ unsigned short sP[8 * 16 * 64];   // 16 KB (wave-private rows)
    // total 80 KB -> 2 blocks/CU; 1024-block grid queues -> HW scheduler rebalances tails

    const int flat = (int)blockIdx.x;
    const int sp   = flat >> 8;                // parity-4 split 0..3
    const int rb   = flat & 255;
    const int n    = (rb + sp) & (NH - 1);     // head remap (bijective per split)
    const int qt   = rb >> 4;
    const int q0   = qt * BQ;
    const int plen = plen_g[n];

    const int ptiles = (plen + 63) >> 6;       // 0..32 prefix tiles (last may be partial)
    const int d0     = q0 >> 6;                // = 2*qt, even
    int td = -1;                               // this split's diag tile (if any)
    if ((d0 & 3) == sp)            td = d0;
    else if (((d0 + 1) & 3) == sp) td = d0 + 1;
    const int cnt_p = (ptiles - sp + 3) >> 2;  // # parity-sp prefix tiles (>=0 for sp<=3)
    const int total = cnt_p + ((td >= 0 && td >= ptiles) ? 1 : 0);
    if (total == 0) return;                    // block-uniform; combine predicate matches

    const int tid  = (int)threadIdx.x;
    const int wave = tid >> 6, lane = tid & 63, quad = lane >> 4, l16 = lane & 15;

    const int qrow  = wave * 16 + l16;
    const int qglob = q0 + qrow;
    const int pmask = (l16 & 7) * 8;           // sP XOR swizzle (bits 3-5; b128-safe)

    const unsigned short* kh = Kb  + (size_t)n * SL * DD;
    const unsigned short* vh = Vtb + (size_t)n * DD * SL;

    // staging lane mapping: each of 8 waves moves one 1KB segment of K and of V per tile
    const int srow = wave * 8 + (lane >> 3);
    const int scol = ((lane & 7) ^ (srow & 7)) * 8;

    auto tile_of = [&](int i) -> int {
        return (i < cnt_p) ? (sp + (i << 2)) : td;
    };
    // stage tile t into buffer b: exactly 2 global_load_lds per wave (K seg + V seg), uniform
    auto stage = [&](int t, int b) {
        const unsigned short* kg = kh + ((size_t)t << 6) * DD;
        const unsigned short* vg = vh + (t << 6);
        gld16(kg + srow * DD + scol, sK[b] + wave * 512);
        gld16(vg + (size_t)srow * SL + scol, sVt[b] + wave * 512);
    };

    // Q fragments (bf16, prescaled in prep)
    const unsigned short* qb = Qb + ((size_t)n * QL + qglob) * DD;
    short8 bQ0 = *(const short8*)(qb + quad * 8);
    short8 bQ1 = *(const short8*)(qb + 32 + quad * 8);

    // ---- prologue: stage pair 0 (tiles 0 and 1 if present) into buffers 0/1 ----
    stage(tile_of(0), 0);
    if (1 < total) stage(tile_of(1), 1);

    floatx4 acc[4];
    #pragma unroll
    for (int dt = 0; dt < 4; ++dt) acc[dt] = (floatx4){0.f, 0.f, 0.f, 0.f};
    float lsum = 0.f;                          // per-lane partial of l for q = qglob
    unsigned short* pw = sP + qrow * 64;

    // one tile's QK -> softmax -> PV (identical numerics to R3/R9)
    auto do_tile = [&](int t, const unsigned short* sk, const unsigned short* sv) {
        const int s0 = t << 6;

        // ---- S^T = K·Q^T : D[s=st2*16+quad*4+r][q=l16] ----
        floatx4 sf[4];
        #pragma unroll
        for (int st2 = 0; st2 < 4; ++st2) sf[st2] = (floatx4){0.f, 0.f, 0.f, 0.f};
        __builtin_amdgcn_s_setprio(1);
        #pragma unroll
        for (int st2 = 0; st2 < 4; ++st2) {
            int krow = st2 * 16 + l16;
            short8 aK0 = *(const short8*)(sk + krow * 64 + (((0 * 4 + quad) ^ (krow & 7)) * 8));
            short8 aK1 = *(const short8*)(sk + krow * 64 + (((1 * 4 + quad) ^ (krow & 7)) * 8));
            sf[st2] = __builtin_amdgcn_mfma_f32_16x16x32_bf16(aK0, bQ0, sf[st2], 0, 0, 0);
            sf[st2] = __builtin_amdgcn_mfma_f32_16x16x32_bf16(aK1, bQ1, sf[st2], 0, 0, 0);
        }
        __builtin_amdgcn_s_setprio(0);

        // ---- fixed-max softmax: p = exp2(prescaled score); no cross-lane ops ----
        if (s0 + 64 <= plen) {                 // fully-valid tile
            #pragma unroll
            for (int st2 = 0; st2 < 4; ++st2) {
                float p0 = __builtin_amdgcn_exp2f(sf[st2][0]);
                float p1 = __builtin_amdgcn_exp2f(sf[st2][1]);
                float p2 = __builtin_amdgcn_exp2f(sf[st2][2]);
                float p3 = __builtin_amdgcn_exp2f(sf[st2][3]);
                lsum += (p0 + p1) + (p2 + p3);
                uint2 pk = { f2bf2u(p0, p1), f2bf2u(p2, p3) };
                *(uint2*)(pw + ((st2 * 16 + quad * 4) ^ pmask)) = pk;   // P^T-pack, swizzled
            }
        } else {                               // partial/diag tile
            #pragma unroll
            for (int st2 = 0; st2 < 4; ++st2) {
                float p[4];
                #pragma unroll
                for (int r2 = 0; r2 < 4; ++r2) {
                    int s = s0 + st2 * 16 + quad * 4 + r2;
                    bool valid = (s < plen) || (s == qglob);
                    p[r2] = __builtin_amdgcn_exp2f(valid ? sf[st2][r2] : -INFINITY);
                    lsum += p[r2];
                }
                uint2 pk = { f2bf2u(p[0], p[1]), f2bf2u(p[2], p[3]) };
                *(uint2*)(pw + ((st2 * 16 + quad * 4) ^ pmask)) = pk;
            }
        }

        // ---- PV: O[q][d] += P·V (A = P rows q, B = V^T rows d) ----
        __builtin_amdgcn_s_setprio(1);
        #pragma unroll
        for (int ks = 0; ks < 2; ++ks) {
            short8 aP = *(const short8*)(pw + ((ks * 32 + quad * 8) ^ pmask));
            #pragma unroll
            for (int dt = 0; dt < 4; ++dt) {
                int vrow = dt * 16 + l16;
                short8 bV = *(const short8*)(sv + vrow * 64 + (((ks * 4 + quad) ^ (vrow & 7)) * 8));
                acc[dt] = __builtin_amdgcn_mfma_f32_16x16x32_bf16(aP, bV, acc[dt], 0, 0, 0);
            }
        }
        __builtin_amdgcn_s_setprio(0);
    };

    const int np = (total + 1) >> 1;           // tile pairs (last may be single)
    for (int p = 0; p < np; ++p) {
        // pair p staged one full pair-compute ago -> drain is ~free; lgkmcnt(0) closes
        // the ds-read window before anyone overwrites the rotated pair buffers.
        asm volatile("s_waitcnt vmcnt(0) lgkmcnt(0)" ::: "memory");
        __builtin_amdgcn_s_barrier();          // all waves' pair-p loads now landed

        const int i0 = 2 * p;
        const int nb = 2 * ((p + 1) & 1);      // next pair's buffer set
        if (i0 + 2 < total) stage(tile_of(i0 + 2), nb);       // block-uniform conditions
        if (i0 + 3 < total) stage(tile_of(i0 + 3), nb + 1);

        const int cb = 2 * (p & 1);            // this pair's buffer set
        do_tile(tile_of(i0), sK[cb], sVt[cb]);
        if (i0 + 1 < total)
            do_tile(tile_of(i0 + 1), sK[cb + 1], sVt[cb + 1]);
    }

    // ---- epilogue: unnormalized partials, bf16, coalesced via per-wave sP transpose ----
    lsum += __shfl_xor(lsum, 16, 64);
    lsum += __shfl_xor(lsum, 32, 64);
    if (quad == 0)
        Lp[((size_t)sp * NH + n) * QL + q0 + qrow] = lsum;

    unsigned short* pws = sP + wave * 16 * 64;   // wave-private region, free after last PV
    #pragma unroll
    for (int dt = 0; dt < 4; ++dt) {
        int chunk = dt * 2 + (l16 >> 3);
        #pragma unroll
        for (int r2 = 0; r2 < 4; ++r2) {
            int row = quad * 4 + r2;
            int sw = ((chunk ^ (row & 7)) * 8) + (l16 & 7);
            pws[row * 64 + sw] = f2bf(acc[dt][r2]);
        }
    }
    const size_t qbase = ((size_t)sp * NH + n) * QL + q0 + wave * 16;
    #pragma unroll
    for (int t2 = 0; t2 < 2; ++t2) {
        int row = t2 * 8 + (lane >> 3);
        int chunk = lane & 7;
        int sw = (chunk ^ (row & 7)) * 8;
        ushort8v val = *(const ushort8v*)(pws + row * 64 + sw);
        *(ushort8v*)(Opb + (qbase + row) * DD + chunk * 8) = val;
    }
}

// ---------------- combine: O = sum_sp(Opb) / sum_sp(Lp), predicated on block-ran ----------------
__global__ __launch_bounds__(512) void k_combine(
    const unsigned short* __restrict__ Opb, const float* __restrict__ Lp,
    const int* __restrict__ plen_g, float* __restrict__ Og)
{
    const int idx = (int)(blockIdx.x * 512 + threadIdx.x);   // 8-elem group, NH*QL*DD/8 = 262144
    const int d8 = idx & 7;
    const int q  = (idx >> 3) & (QL - 1);
    const int n  = idx >> 14;
    const int plen   = plen_g[n];
    const int ptiles = (plen + 63) >> 6;
    const int d0     = (q >> 7) << 1;          // block diag base tile for q's q-tile
    const int dp0    = d0 & 3;
    const int dp1    = (d0 + 1) & 3;
    float s[8];
    #pragma unroll
    for (int j = 0; j < 8; ++j) s[j] = 0.f;
    float l = 0.f;
    #pragma unroll
    for (int sp = 0; sp < NSPLIT; ++sp) {
        // predicate == "block (sp, q>>7) ran": prefix non-empty OR owns a diag tile
        if ((ptiles > sp) || (sp == dp0) || (sp == dp1)) {
            const unsigned short* ob = Opb + (((size_t)sp * NH + n) * QL + q) * DD + d8 * 8;
            ushort8v v = *(const ushort8v*)ob;
            #pragma unroll
            for (int j = 0; j < 8; ++j) s[j] += bf2f(v[j]);
            l += Lp[((size_t)sp * NH + n) * QL + q];
        }
    }
    const float inv = 1.0f / l;                // l > 0: q's diag-col split always contributes
    float4 o0 = { s[0] * inv, s[1] * inv, s[2] * inv, s[3] * inv };
    float4 o1 = { s[4] * inv, s[5] * inv, s[6] * inv, s[7] * inv };
    float* og = Og + ((size_t)n * QL + q) * DD + d8 * 8;
    *(float4*)og = o0;
    *(float4*)(og + 4) = o1;
}

extern "C" void kernel_launch(void* const* d_in, const int* in_sizes, int n_in,
                              void* d_out, int out_size, void* d_ws, size_t ws_size,
                              hipStream_t stream) {
    const float* Qf   = (const float*)d_in[0];
    const float* Kf   = (const float*)d_in[1];
    const float* Vf   = (const float*)d_in[2];
    const int*   plen = (const int*)d_in[3];
    float* Og = (float*)d_out;

    char* ws = (char*)d_ws;
    unsigned short* Kb  = (unsigned short*)(ws);                 // 4 MB
    unsigned short* Vtb = (unsigned short*)(ws + (4u << 20));    // 4 MB
    unsigned short* Qb  = (unsigned short*)(ws + (8u << 20));    // 4 MB
    unsigned short* Opb = (unsigned short*)(ws + (12u << 20));   // NSPLIT * 4 MB = 16 MB
    float*          Lp  = (float*)(ws + (28u << 20));            // NSPLIT * 128 KB

    k_prep<<<512, 512, 0, stream>>>(Qf, Kf, Vf, Qb, Kb, Vtb);
    k_attn<<<NSPLIT * 256, 512, 0, stream>>>(Qb, Kb, Vtb, plen, Opb, Lp);
    k_combine<<<512, 512, 0, stream>>>(Opb, Lp, plen, Og);
}

// Round 12
// 104.028 us; speedup vs baseline: 1.0209x; 1.0209x over previous
//
#include <hip/hip_runtime.h>
#include <hip/hip_bf16.h>
#include <math.h>

#define NH 16
#define QL 2048
#define SL 2048
#define DD 64
#define BQ 128
#define NSPLIT 2
#define PSTR 72
#define QK_SCALE_LOG2E 0.1803368801111f   // (8/64) * log2(e): fold softmax scale + ln2 into Q

typedef __attribute__((ext_vector_type(8))) short short8;
typedef __attribute__((ext_vector_type(4))) float floatx4;
typedef __attribute__((ext_vector_type(4))) unsigned short ushort4v;
typedef __attribute__((ext_vector_type(8))) unsigned short ushort8v;

__device__ __forceinline__ unsigned short f2bf(float x) {   // RNE fp32->bf16
    unsigned u = __float_as_uint(x);
    u += 0x7FFFu + ((u >> 16) & 1u);
    return (unsigned short)(u >> 16);
}
__device__ __forceinline__ unsigned int f2bf2u(float x, float y) {  // packed pair (low=x)
    __hip_bfloat162 h = __float22bfloat162_rn(make_float2(x, y));
    return *(unsigned int*)&h;
}
__device__ __forceinline__ float bf2f(unsigned short h) {
    return __uint_as_float((unsigned)h << 16);
}

// async global->LDS, 16B per lane; LDS dest = wave-uniform base + lane*16
__device__ __forceinline__ void gld16(const unsigned short* g, unsigned short* l) {
    __builtin_amdgcn_global_load_lds(
        (const __attribute__((address_space(1))) unsigned int*)g,
        (__attribute__((address_space(3))) unsigned int*)l, 16, 0, 0);
}

// ---------------- prep: K->bf16 + V->V^T bf16, one 512x512 launch ----------------
__global__ __launch_bounds__(512) void k_prep(
    const float* __restrict__ Kf, const float* __restrict__ Vf,
    unsigned short* __restrict__ Kb, unsigned short* __restrict__ Vtb)
{
    __shared__ unsigned short sT[64][PSTR];    // 9 KB: V-transpose scratch
    const int bx = (int)blockIdx.x, tid = (int)threadIdx.x;

    // K convert: NH*SL*DD/4 = 524288 float4 groups, 2 per thread
    const int gidx = bx * 512 + tid;
    #pragma unroll
    for (int k = 0; k < 2; ++k) {
        int idx = gidx + k * (512 * 512);
        float4 v = ((const float4*)Kf)[idx];
        ushort4v h = { f2bf(v.x), f2bf(v.y), f2bf(v.z), f2bf(v.w) };
        *(ushort4v*)(Kb + (size_t)idx * 4) = h;
    }

    // V transpose: block bx owns s-tile bx (16 heads x 32 tiles = 512)
    const int n = bx >> 5, s0 = (bx & 31) * 64;
    const float* vb = Vf + ((size_t)n * SL + s0) * DD;
    #pragma unroll
    for (int i = 0; i < 2; ++i) {
        int idx = tid + i * 512;
        int r = idx >> 4, c = (idx & 15) << 2;
        float4 v = *(const float4*)(vb + r * DD + c);
        sT[c + 0][r] = f2bf(v.x);
        sT[c + 1][r] = f2bf(v.y);
        sT[c + 2][r] = f2bf(v.z);
        sT[c + 3][r] = f2bf(v.w);
    }
    __syncthreads();
    const int d = tid >> 3, sg = tid & 7;
    unsigned short* out = Vtb + (size_t)n * DD * SL + (size_t)d * SL + s0 + sg * 8;
    ushort8v a;
    #pragma unroll
    for (int i = 0; i < 8; ++i) a[i] = sT[d][sg * 8 + i];
    *(ushort8v*)out = a;
}

// ---------------- attention: parity split-S(2), TWO tiles per barrier segment (pair pipeline) --------
// Split sp owns s-tiles with (tile & 1) == sp; diag tile d0+sp has parity sp -> every block >= 1 tile.
// 4 LDS tile-buffers = pair-level double buffer. Per segment: drain+barrier, stage next pair,
// compute tile 2p then 2p+1 (independent chains -> compiler overlaps QK(2p+1) under SM/PV(2p)).
__global__ __launch_bounds__(512, 4) void k_attn(
    const float* __restrict__ Qf, const unsigned short* __restrict__ Kb,
    const unsigned short* __restrict__ Vtb, const int* __restrict__ plen_g,
    unsigned short* __restrict__ Opb, float* __restrict__ Lp)
{
    // K/V: 64x64 bf16 tiles, row = 64 ushorts (128B, NO pad: global_load_lds needs lane*16 dest),
    // chunk c of row r at slot c ^ (r&7) (swizzle on the global fetch side).
    __shared__ unsigned short sK[4][64 * 64];    // 32 KB: 2 pairs x 2 tiles
    __shared__ unsigned short sVt[4][64 * 64];   // 32 KB
    __shared__ unsigned short sP[8 * 16 * 64];   // 16 KB (wave-private rows)
    // total 80 KB -> exactly 2 blocks/CU

    const int flat = (int)blockIdx.x;
    const int sp   = flat >> 8;                // parity split 0/1
    const int rb   = flat & 255;
    const int n    = (rb + sp) & (NH - 1);     // head remap (bijective per split)
    const int qt   = rb >> 4;
    const int q0   = qt * BQ;
    const int plen = plen_g[n];

    const int tid  = (int)threadIdx.x;
    const int wave = tid >> 6, lane = tid & 63, quad = lane >> 4, l16 = lane & 15;

    const int ptiles = (plen + 63) >> 6;       // 0..32 prefix tiles (last may be partial)
    const int d0     = q0 >> 6;                // even
    const int tdiag  = d0 + sp;                // the parity-sp diag tile
    const int cnt_p  = (ptiles + 1 - sp) >> 1; // # parity-sp prefix tiles (>=0)
    const int total  = cnt_p + (tdiag >= ptiles ? 1 : 0);   // >= 1 always

    const int qrow  = wave * 16 + l16;
    const int qglob = q0 + qrow;
    const int pmask = (l16 & 7) * 8;           // sP XOR swizzle (bits 3-5; b128-safe)

    const unsigned short* kh = Kb  + (size_t)n * SL * DD;
    const unsigned short* vh = Vtb + (size_t)n * DD * SL;

    // staging lane mapping: each of 8 waves moves one 1KB segment of K and of V per tile
    const int srow = wave * 8 + (lane >> 3);
    const int scol = ((lane & 7) ^ (srow & 7)) * 8;

    auto tile_of = [&](int i) -> int {
        return (i < cnt_p) ? (sp + (i << 1)) : tdiag;
    };
    // stage tile t into buffer b: exactly 2 global_load_lds per wave (K seg + V seg), uniform
    auto stage = [&](int t, int b) {
        const unsigned short* kg = kh + ((size_t)t << 6) * DD;
        const unsigned short* vg = vh + (t << 6);
        gld16(kg + srow * DD + scol, sK[b] + wave * 512);
        gld16(vg + (size_t)srow * SL + scol, sVt[b] + wave * 512);
    };

    // Q fragments first (their consumption wait leaves later stage-loads in flight)
    short8 bQ0, bQ1;
    {
        const float* qf = Qf + ((size_t)(n * QL + qglob)) * DD + quad * 8;
        float4 a0 = *(const float4*)(qf);
        float4 a1 = *(const float4*)(qf + 4);
        float4 c0 = *(const float4*)(qf + 32);
        float4 c1 = *(const float4*)(qf + 36);
        const float S = QK_SCALE_LOG2E;
        unsigned int u0[4] = {
            f2bf2u(a0.x * S, a0.y * S), f2bf2u(a0.z * S, a0.w * S),
            f2bf2u(a1.x * S, a1.y * S), f2bf2u(a1.z * S, a1.w * S) };
        unsigned int u1[4] = {
            f2bf2u(c0.x * S, c0.y * S), f2bf2u(c0.z * S, c0.w * S),
            f2bf2u(c1.x * S, c1.y * S), f2bf2u(c1.z * S, c1.w * S) };
        bQ0 = *(short8*)u0;
        bQ1 = *(short8*)u1;
    }

    // ---- prologue: stage pair 0 (tiles 0 and 1 if present) into buffers 0/1 ----
    stage(tile_of(0), 0);
    if (1 < total) stage(tile_of(1), 1);

    floatx4 acc[4];
    #pragma unroll
    for (int dt = 0; dt < 4; ++dt) acc[dt] = (floatx4){0.f, 0.f, 0.f, 0.f};
    float lsum = 0.f;                          // per-lane partial of l for q = qglob
    unsigned short* pw = sP + qrow * 64;

    // one tile's QK -> softmax -> PV (identical numerics to R3)
    auto do_tile = [&](int t, const unsigned short* sk, const unsigned short* sv) {
        const int s0 = t << 6;

        // ---- S^T = K·Q^T : D[s=st2*16+quad*4+r][q=l16] ----
        floatx4 sf[4];
        #pragma unroll
        for (int st2 = 0; st2 < 4; ++st2) sf[st2] = (floatx4){0.f, 0.f, 0.f, 0.f};
        __builtin_amdgcn_s_setprio(1);
        #pragma unroll
        for (int st2 = 0; st2 < 4; ++st2) {
            int krow = st2 * 16 + l16;
            short8 aK0 = *(const short8*)(sk + krow * 64 + (((0 * 4 + quad) ^ (krow & 7)) * 8));
            short8 aK1 = *(const short8*)(sk + krow * 64 + (((1 * 4 + quad) ^ (krow & 7)) * 8));
            sf[st2] = __builtin_amdgcn_mfma_f32_16x16x32_bf16(aK0, bQ0, sf[st2], 0, 0, 0);
            sf[st2] = __builtin_amdgcn_mfma_f32_16x16x32_bf16(aK1, bQ1, sf[st2], 0, 0, 0);
        }
        __builtin_amdgcn_s_setprio(0);

        // ---- fixed-max softmax: p = exp2(prescaled score); no cross-lane ops ----
        if (s0 + 64 <= plen) {                 // fully-valid tile
            #pragma unroll
            for (int st2 = 0; st2 < 4; ++st2) {
                float p0 = __builtin_amdgcn_exp2f(sf[st2][0]);
                float p1 = __builtin_amdgcn_exp2f(sf[st2][1]);
                float p2 = __builtin_amdgcn_exp2f(sf[st2][2]);
                float p3 = __builtin_amdgcn_exp2f(sf[st2][3]);
                lsum += (p0 + p1) + (p2 + p3);
                uint2 pk = { f2bf2u(p0, p1), f2bf2u(p2, p3) };
                *(uint2*)(pw + ((st2 * 16 + quad * 4) ^ pmask)) = pk;   // P^T-pack, swizzled
            }
        } else {                               // partial/diag tile
            #pragma unroll
            for (int st2 = 0; st2 < 4; ++st2) {
                float p[4];
                #pragma unroll
                for (int r2 = 0; r2 < 4; ++r2) {
                    int s = s0 + st2 * 16 + quad * 4 + r2;
                    bool valid = (s < plen) || (s == qglob);
                    p[r2] = __builtin_amdgcn_exp2f(valid ? sf[st2][r2] : -INFINITY);
                    lsum += p[r2];
                }
                uint2 pk = { f2bf2u(p[0], p[1]), f2bf2u(p[2], p[3]) };
                *(uint2*)(pw + ((st2 * 16 + quad * 4) ^ pmask)) = pk;
            }
        }

        // ---- PV: O[q][d] += P·V (A = P rows q, B = V^T rows d) ----
        __builtin_amdgcn_s_setprio(1);
        #pragma unroll
        for (int ks = 0; ks < 2; ++ks) {
            short8 aP = *(const short8*)(pw + ((ks * 32 + quad * 8) ^ pmask));
            #pragma unroll
            for (int dt = 0; dt < 4; ++dt) {
                int vrow = dt * 16 + l16;
                short8 bV = *(const short8*)(sv + vrow * 64 + (((ks * 4 + quad) ^ (vrow & 7)) * 8));
                acc[dt] = __builtin_amdgcn_mfma_f32_16x16x32_bf16(aP, bV, acc[dt], 0, 0, 0);
            }
        }
        __builtin_amdgcn_s_setprio(0);
    };

    const int np = (total + 1) >> 1;           // tile pairs (last may be single)
    for (int p = 0; p < np; ++p) {
        // pair p staged one full pair-compute ago -> drain is ~free; lgkmcnt(0) closes
        // the ds-read window before anyone overwrites the rotated pair buffers.
        asm volatile("s_waitcnt vmcnt(0) lgkmcnt(0)" ::: "memory");
        __builtin_amdgcn_s_barrier();          // all waves' pair-p loads now landed

        const int i0 = 2 * p;
        const int nb = 2 * ((p + 1) & 1);      // next pair's buffer set
        if (i0 + 2 < total) stage(tile_of(i0 + 2), nb);       // block-uniform conditions
        if (i0 + 3 < total) stage(tile_of(i0 + 3), nb + 1);

        const int cb = 2 * (p & 1);            // this pair's buffer set
        do_tile(tile_of(i0), sK[cb], sVt[cb]);
        if (i0 + 1 < total)
            do_tile(tile_of(i0 + 1), sK[cb + 1], sVt[cb + 1]);
    }

    // ---- epilogue: unnormalized partials, bf16, coalesced via per-wave sP transpose ----
    lsum += __shfl_xor(lsum, 16, 64);
    lsum += __shfl_xor(lsum, 32, 64);
    if (quad == 0)
        Lp[((size_t)sp * NH + n) * QL + q0 + qrow] = lsum;

    unsigned short* pws = sP + wave * 16 * 64;   // wave-private region, free after last PV
    #pragma unroll
    for (int dt = 0; dt < 4; ++dt) {
        int chunk = dt * 2 + (l16 >> 3);
        #pragma unroll
        for (int r2 = 0; r2 < 4; ++r2) {
            int row = quad * 4 + r2;
            int sw = ((chunk ^ (row & 7)) * 8) + (l16 & 7);
            pws[row * 64 + sw] = f2bf(acc[dt][r2]);
        }
    }
    const size_t qbase = ((size_t)sp * NH + n) * QL + q0 + wave * 16;
    #pragma unroll
    for (int t2 = 0; t2 < 2; ++t2) {
        int row = t2 * 8 + (lane >> 3);
        int chunk = lane & 7;
        int sw = (chunk ^ (row & 7)) * 8;
        ushort8v val = *(const ushort8v*)(pws + row * 64 + sw);
        *(ushort8v*)(Opb + (qbase + row) * DD + chunk * 8) = val;
    }
}

// ---------------- combine: O = (Opb[0]+Opb[1]) / (Lp[0]+Lp[1]); branchless ----------------
__global__ __launch_bounds__(512) void k_combine(
    const unsigned short* __restrict__ Opb, const float* __restrict__ Lp,
    float* __restrict__ Og)
{
    const int idx = (int)(blockIdx.x * 512 + threadIdx.x);   // 8-elem group, NH*QL*DD/8 = 262144
    const int d8 = idx & 7;
    const int q  = (idx >> 3) & (QL - 1);
    const int n  = idx >> 14;
    float s[8];
    #pragma unroll
    for (int j = 0; j < 8; ++j) s[j] = 0.f;
    float l = 0.f;
    #pragma unroll
    for (int sp = 0; sp < NSPLIT; ++sp) {      // parity split: both ALWAYS contribute
        const unsigned short* ob = Opb + (((size_t)sp * NH + n) * QL + q) * DD + d8 * 8;
        ushort8v v = *(const ushort8v*)ob;
        #pragma unroll
        for (int j = 0; j < 8; ++j) s[j] += bf2f(v[j]);
        l += Lp[((size_t)sp * NH + n) * QL + q];
    }
    const float inv = 1.0f / l;                // l > 0: diag col always unmasked in one split
    float4 o0 = { s[0] * inv, s[1] * inv, s[2] * inv, s[3] * inv };
    float4 o1 = { s[4] * inv, s[5] * inv, s[6] * inv, s[7] * inv };
    float* og = Og + ((size_t)n * QL + q) * DD + d8 * 8;
    *(float4*)og = o0;
    *(float4*)(og + 4) = o1;
}

extern "C" void kernel_launch(void* const* d_in, const int* in_sizes, int n_in,
                              void* d_out, int out_size, void* d_ws, size_t ws_size,
                              hipStream_t stream) {
    const float* Qf   = (const float*)d_in[0];
    const float* Kf   = (const float*)d_in[1];
    const float* Vf   = (const float*)d_in[2];
    const int*   plen = (const int*)d_in[3];
    float* Og = (float*)d_out;

    char* ws = (char*)d_ws;
    unsigned short* Kb  = (unsigned short*)(ws);                 // 4 MB
    unsigned short* Vtb = (unsigned short*)(ws + (4u << 20));    // 4 MB
    unsigned short* Opb = (unsigned short*)(ws + (8u << 20));    // NSPLIT * 4 MB
    float*          Lp  = (float*)(ws + (16u << 20));            // NSPLIT * 128 KB

    k_prep<<<512, 512, 0, stream>>>(Kf, Vf, Kb, Vtb);
    k_attn<<<NSPLIT * 256, 512, 0, stream>>>(Qf, Kb, Vtb, plen, Opb, Lp);
    k_combine<<<512, 512, 0, stream>>>(Opb, Lp, Og);
}